// Round 1
// baseline (191.483 us; speedup 1.0000x reference)
//
#include <hip/hip_runtime.h>
#include <math.h>

// Problem constants (reference: B=16, C=256, H=80, W=80, K=3, ALPHA=0.1, EPS=1e-7)
#define L_LEN 6400        // H*W
#define NROWS 4096        // B*C
#define C_CH 256
#define TPB 320           // 5 waves of 64
#define VPT 20            // elements per thread: 320*20 = 6400
// log2(0.9) in double precision
#define LOG2_DECAY -0.15200309344504997

__global__ __launch_bounds__(TPB) void ema_attn_kernel(
    const float* __restrict__ x,
    const float* __restrict__ conv_w,   // [C,1,3]
    const float* __restrict__ conv_b,   // [C]
    float* __restrict__ out)
{
    const int row  = blockIdx.x;          // b*C + c
    const int c    = row & (C_CH - 1);
    const long row_off = (long)row * L_LEN;
    const int t    = threadIdx.x;
    const int start = t * VPT;            // position of this thread's chunk in the row

    // ---- load 20 contiguous elements as 5 float4 (16B-aligned: start*4 = 80t bytes) ----
    const float4* xp4 = (const float4*)(x + row_off + start);
    float xv[VPT];
    #pragma unroll
    for (int i = 0; i < 5; ++i) {
        float4 v = xp4[i];
        xv[4*i+0] = v.x; xv[4*i+1] = v.y; xv[4*i+2] = v.z; xv[4*i+3] = v.w;
    }

    // ---- local weighted sum (pass 1): s = sum_j x[j] * (0.1 * 0.9^(start+j)) ----
    const double d0 = exp2((double)start * LOG2_DECAY);  // matches f64->f32 reference decay
    float decay = (float)d0;
    float s = 0.f;
    #pragma unroll
    for (int j = 0; j < VPT; ++j) {
        s += xv[j] * (0.1f * decay);
        decay *= 0.9f;
    }

    // ---- block-wide exclusive scan of thread sums ----
    const int lane = t & 63;
    const int wid  = t >> 6;              // 0..4
    float inc = s;
    #pragma unroll
    for (int off = 1; off < 64; off <<= 1) {
        float n = __shfl_up(inc, off, 64);
        if (lane >= off) inc += n;
    }
    __shared__ float wsum[TPB / 64];
    if (lane == 63) wsum[wid] = inc;
    __syncthreads();
    float excl = inc - s;                 // exclusive within wave
    #pragma unroll
    for (int wprev = 0; wprev < TPB / 64; ++wprev) {
        if (wprev < wid) excl += wsum[wprev];
    }

    // ---- conv neighbors across chunk edges (row-padding with zeros) ----
    const float xl = (start == 0)         ? 0.f : x[row_off + start - 1];
    const float xr = (start + VPT == L_LEN) ? 0.f : x[row_off + start + VPT];
    const float w0 = conv_w[c*3 + 0];
    const float w1 = conv_w[c*3 + 1];
    const float w2 = conv_w[c*3 + 2];
    const float bias = conv_b[c];

    // ---- pass 2: ema + conv + residual ----
    float o[VPT];
    decay = (float)d0;
    float cum = excl;
    #pragma unroll
    for (int j = 0; j < VPT; ++j) {
        cum += xv[j] * (0.1f * decay);
        // cumsum_decay closed form: 1 - 0.9^(i+1) = 1 - 0.9*decay_i
        float cd = 1.0f - 0.9f * decay;
        decay *= 0.9f;
        float ema = cum / (cd + 1e-7f);
        float prev = (j == 0)       ? xl : xv[j-1];
        float nxt  = (j == VPT-1)   ? xr : xv[j+1];
        float conv = w0 * prev + w1 * xv[j] + w2 * nxt + bias;
        o[j] = ema + conv + xv[j];
    }

    // ---- coalesced-ish float4 stores ----
    float4* op4 = (float4*)(out + row_off + start);
    #pragma unroll
    for (int i = 0; i < 5; ++i) {
        op4[i] = make_float4(o[4*i+0], o[4*i+1], o[4*i+2], o[4*i+3]);
    }
}

extern "C" void kernel_launch(void* const* d_in, const int* in_sizes, int n_in,
                              void* d_out, int out_size, void* d_ws, size_t ws_size,
                              hipStream_t stream) {
    const float* x      = (const float*)d_in[0];
    const float* conv_w = (const float*)d_in[1];
    const float* conv_b = (const float*)d_in[2];
    float* out          = (float*)d_out;
    ema_attn_kernel<<<NROWS, TPB, 0, stream>>>(x, conv_w, conv_b, out);
}

// Round 2
// 189.779 us; speedup vs baseline: 1.0090x; 1.0090x over previous
//
#include <hip/hip_runtime.h>
#include <math.h>

// Problem constants (reference: B=16, C=256, H=80, W=80, K=3, ALPHA=0.1, EPS=1e-7)
#define L_LEN 6400        // H*W
#define NROWS 4096        // B*C
#define C_CH 256
#define TPB 320           // 5 waves of 64
#define VPT 20            // elements per thread: 320*20 = 6400
#define NV4 (L_LEN / 4)   // 1600 float4 per row
// log2(0.9) in double precision
#define LOG2_DECAY -0.15200309344504997

__global__ __launch_bounds__(TPB) void ema_attn_kernel(
    const float* __restrict__ x,
    const float* __restrict__ conv_w,   // [C,1,3]
    const float* __restrict__ conv_b,   // [C]
    float* __restrict__ out)
{
    __shared__ float sx[L_LEN];           // 25.6 KB: row staging (in, then out)
    __shared__ float wsum[TPB / 64];

    const int row  = blockIdx.x;          // b*C + c
    const int c    = row & (C_CH - 1);
    const long row_off = (long)row * L_LEN;
    const int t    = threadIdx.x;
    const int start = t * VPT;            // position of this thread's chunk in the row

    // ---- Phase A: coalesced global -> LDS (16B/lane, lane-contiguous) ----
    const float4* gx  = (const float4*)(x + row_off);
    float4*       sx4 = (float4*)sx;
    #pragma unroll
    for (int k = 0; k < 5; ++k) {
        sx4[k * TPB + t] = gx[k * TPB + t];
    }
    __syncthreads();

    // ---- Phase B: per-thread contiguous chunk from LDS ----
    const float4* my4 = (const float4*)(sx + start);
    float xv[VPT];
    #pragma unroll
    for (int i = 0; i < 5; ++i) {
        float4 v = my4[i];
        xv[4*i+0] = v.x; xv[4*i+1] = v.y; xv[4*i+2] = v.z; xv[4*i+3] = v.w;
    }
    // conv neighbors across chunk edges (zero padding at row ends)
    const float xl = (start == 0)           ? 0.f : sx[start - 1];
    const float xr = (start + VPT == L_LEN) ? 0.f : sx[start + VPT];

    // ---- local weighted sum: s = sum_j x[j] * (0.1 * 0.9^(start+j)) ----
    const double d0 = exp2((double)start * LOG2_DECAY);  // matches f64->f32 reference decay
    float decay = (float)d0;
    float s = 0.f;
    #pragma unroll
    for (int j = 0; j < VPT; ++j) {
        s += xv[j] * (0.1f * decay);
        decay *= 0.9f;
    }

    // ---- block-wide exclusive scan of thread sums ----
    const int lane = t & 63;
    const int wid  = t >> 6;              // 0..4
    float inc = s;
    #pragma unroll
    for (int off = 1; off < 64; off <<= 1) {
        float n = __shfl_up(inc, off, 64);
        if (lane >= off) inc += n;
    }
    if (lane == 63) wsum[wid] = inc;
    __syncthreads();                      // also: all Phase-B reads done before overwrite
    float excl = inc - s;                 // exclusive within wave
    #pragma unroll
    for (int wprev = 0; wprev < TPB / 64; ++wprev) {
        if (wprev < wid) excl += wsum[wprev];
    }

    const float w0 = conv_w[c*3 + 0];
    const float w1 = conv_w[c*3 + 1];
    const float w2 = conv_w[c*3 + 2];
    const float bias = conv_b[c];

    // ---- pass 2: ema + conv + residual ----
    float o[VPT];
    decay = (float)d0;
    float cum = excl;
    #pragma unroll
    for (int j = 0; j < VPT; ++j) {
        cum += xv[j] * (0.1f * decay);
        // cumsum_decay closed form: 1 - 0.9^(i+1) = 1 - 0.9*decay_i
        float cd = 1.0f - 0.9f * decay;
        decay *= 0.9f;
        float ema = cum / (cd + 1e-7f);
        float prev = (j == 0)       ? xl : xv[j-1];
        float nxt  = (j == VPT-1)   ? xr : xv[j+1];
        float conv = w0 * prev + w1 * xv[j] + w2 * nxt + bias;
        o[j] = ema + conv + xv[j];
    }

    // ---- write outputs back into LDS (overwrites x; reads all done) ----
    float4* my4w = (float4*)(sx + start);
    #pragma unroll
    for (int i = 0; i < 5; ++i) {
        my4w[i] = make_float4(o[4*i+0], o[4*i+1], o[4*i+2], o[4*i+3]);
    }
    __syncthreads();

    // ---- Phase C: coalesced LDS -> global ----
    float4* go = (float4*)(out + row_off);
    #pragma unroll
    for (int k = 0; k < 5; ++k) {
        go[k * TPB + t] = sx4[k * TPB + t];
    }
}

extern "C" void kernel_launch(void* const* d_in, const int* in_sizes, int n_in,
                              void* d_out, int out_size, void* d_ws, size_t ws_size,
                              hipStream_t stream) {
    const float* x      = (const float*)d_in[0];
    const float* conv_w = (const float*)d_in[1];
    const float* conv_b = (const float*)d_in[2];
    float* out          = (float*)d_out;
    ema_attn_kernel<<<NROWS, TPB, 0, stream>>>(x, conv_w, conv_b, out);
}

// Round 4
// 189.015 us; speedup vs baseline: 1.0131x; 1.0040x over previous
//
#include <hip/hip_runtime.h>
#include <math.h>

// Problem constants (reference: B=16, C=256, H=80, W=80, K=3, ALPHA=0.1, EPS=1e-7)
#define L_LEN 6400        // H*W
#define NROWS 4096        // B*C
#define C_CH 256
#define TPB 320           // 5 waves of 64
#define VPT 20            // elements per thread
#define GRID 1024
#define ITERS (NROWS / GRID)   // 4 rows per block
// log2(0.9) in float
#define LOG2_DECAY_F -0.15200309f

typedef float v4f __attribute__((ext_vector_type(4)));   // native vec4 (builtin-compatible)

// Async global->LDS prefetch of one full row (25.6 KB) in 5 wave-issues/thread.
// LDS dest must be wave-uniform base + lane*16 (m104/m108): our layout is
// lane-contiguous float4, so base = k*TPB + (t & ~63).
__device__ __forceinline__ void prefetch_row(const v4f* gsrc, v4f* ldst, int t) {
    const int wbase = t & ~63;
#pragma unroll
    for (int k = 0; k < 5; ++k) {
        __builtin_amdgcn_global_load_lds(
            (__attribute__((address_space(1))) void*)(gsrc + k * TPB + t),
            (__attribute__((address_space(3))) void*)(ldst + k * TPB + wbase),
            16, 0, 0);
    }
}

__global__ __launch_bounds__(TPB) void ema_attn_kernel(
    const float* __restrict__ x,
    const float* __restrict__ conv_w,   // [C,1,3]
    const float* __restrict__ conv_b,   // [C]
    float* __restrict__ out)
{
    __shared__ __align__(16) float sbuf[2][L_LEN];   // 51.2 KB double buffer
    __shared__ float wsum[TPB / 64];

    const int bid  = blockIdx.x;
    const int t    = threadIdx.x;
    const int lane = t & 63;
    const int wid  = t >> 6;
    const int start = t * VPT;
    const int c    = bid & (C_CH - 1);   // GRID % C_CH == 0 -> channel fixed per block

    const float w0   = conv_w[c * 3 + 0];
    const float w1   = conv_w[c * 3 + 1];
    const float w2   = conv_w[c * 3 + 2];
    const float bias = conv_b[c];

    // 0.9^start; for start beyond ~990 reference f32 decay underflows to 0 anyway
    const float d0 = exp2f((float)start * LOG2_DECAY_F);

    // prime the pipeline: row 'bid' -> buf 0
    prefetch_row((const v4f*)(x + (long)bid * L_LEN), (v4f*)sbuf[0], t);
    __syncthreads();   // drains vmcnt -> buf 0 ready

    for (int it = 0; it < ITERS; ++it) {
        const long row = bid + (long)it * GRID;
        float* cur = sbuf[it & 1];
        float* nxt = sbuf[(it & 1) ^ 1];

        // ---- pass 1: chunk + conv neighbors from LDS, weighted local dot ----
        float xv[VPT];
        const v4f* my4 = (const v4f*)(cur + start);
#pragma unroll
        for (int i = 0; i < 5; ++i) {
            v4f v = my4[i];
            xv[4*i+0] = v.x; xv[4*i+1] = v.y; xv[4*i+2] = v.z; xv[4*i+3] = v.w;
        }
        const float xl = (start == 0)           ? 0.f : cur[start - 1];
        const float xr = (start + VPT == L_LEN) ? 0.f : cur[start + VPT];

        float p = 0.f, w = 0.1f;            // w = 0.1*0.9^j, constant-folded chain
#pragma unroll
        for (int j = 0; j < VPT; ++j) { p = fmaf(xv[j], w, p); w *= 0.9f; }
        const float s = d0 * p;

        // ---- block scan of thread sums ----
        float inc = s;
#pragma unroll
        for (int off = 1; off < 64; off <<= 1) {
            float n = __shfl_up(inc, off, 64);
            if (lane >= off) inc += n;
        }
        if (lane == 63) wsum[wid] = inc;
        __syncthreads();                    // barrier 1: scan partials + all cur reads done

        // issue async prefetch of next row; completes under pass-2 compute
        if (it < ITERS - 1)
            prefetch_row((const v4f*)(x + (row + GRID) * L_LEN), (v4f*)nxt, t);

        float excl = inc - s;
#pragma unroll
        for (int wp = 0; wp < TPB / 64; ++wp)
            if (wp < wid) excl += wsum[wp];

        // ---- pass 2: ema + conv + residual, outputs back into cur ----
        float o[VPT];
        float pj = 0.f; w = 0.1f;
#pragma unroll
        for (int j = 0; j < VPT; ++j) {
            pj = fmaf(xv[j], w, pj);                      // partial weighted dot
            float cum = fmaf(d0, pj, excl);
            float cd  = fmaf(-d0, 9.0f * w, 1.0f) + 1e-7f; // 1 - 0.9^(start+j+1) + eps
            float ema = cum * __builtin_amdgcn_rcpf(cd);
            float prev = (j == 0)       ? xl : xv[j-1];
            float nx   = (j == VPT-1)   ? xr : xv[j+1];
            float conv = fmaf(w0, prev, fmaf(w1, xv[j], fmaf(w2, nx, bias)));
            o[j] = ema + conv + xv[j];
            w *= 0.9f;
        }
        v4f* my4w = (v4f*)(cur + start);
#pragma unroll
        for (int i = 0; i < 5; ++i) {
            v4f ov = { o[4*i+0], o[4*i+1], o[4*i+2], o[4*i+3] };
            my4w[i] = ov;
        }
        __syncthreads();                    // barrier 2: outputs ready (also drains prefetch)

        // ---- coalesced nontemporal store from LDS ----
        v4f* go = (v4f*)(out + row * L_LEN);
        const v4f* c4 = (const v4f*)cur;
#pragma unroll
        for (int k = 0; k < 5; ++k)
            __builtin_nontemporal_store(c4[k * TPB + t], go + k * TPB + t);
        // no barrier needed here: next iter's prefetch targets the OTHER buffer,
        // and barrier 1 of next iter orders these LDS reads before its overwrite
    }
}

extern "C" void kernel_launch(void* const* d_in, const int* in_sizes, int n_in,
                              void* d_out, int out_size, void* d_ws, size_t ws_size,
                              hipStream_t stream) {
    const float* x      = (const float*)d_in[0];
    const float* conv_w = (const float*)d_in[1];
    const float* conv_b = (const float*)d_in[2];
    float* out          = (float*)d_out;
    ema_attn_kernel<<<GRID, TPB, 0, stream>>>(x, conv_w, conv_b, out);
}